// Round 15
// baseline (294.018 us; speedup 1.0000x reference)
//
#include <hip/hip_runtime.h>

typedef unsigned short u16;
typedef __attribute__((ext_vector_type(4))) float f32x4;
typedef __attribute__((ext_vector_type(16))) float f32x16;
typedef __attribute__((ext_vector_type(8))) short bf16x8;

#define DEV static __device__ __forceinline__

DEV float bf2f(u16 u) { unsigned int i = ((unsigned int)u) << 16; return __builtin_bit_cast(float, i); }
DEV u16 f2bf(float f) {
  unsigned int x = __builtin_bit_cast(unsigned int, f);
  x += 0x7fffu + ((x >> 16) & 1u);
  return (u16)(x >> 16);
}

// HW pack: one instr for 2 f32 -> 2 bf16 (RNE). No builtin on gfx950 (T12 recipe).
DEV unsigned cvtpk(float lo, float hi) {
  unsigned r;
  asm("v_cvt_pk_bf16_f32 %0, %1, %2" : "=v"(r) : "v"(lo), "v"(hi));
  return r;
}
// Raw 2^x (softmax kept in log2 domain; Q pre-scaled by log2e).
DEV float exp2a(float x) {
  float r;
  asm("v_exp_f32 %0, %1" : "=v"(r) : "v"(x));
  return r;
}

template <int N>
DEV void wait_vmcnt() {
  if constexpr (N == 0) asm volatile("s_waitcnt vmcnt(0)" ::: "memory");
  else if constexpr (N == 3) asm volatile("s_waitcnt vmcnt(3)" ::: "memory");
  else if constexpr (N == 4) asm volatile("s_waitcnt vmcnt(4)" ::: "memory");
  else static_assert(N == 0, "unsupported vmcnt");
}

DEV void gload16(const u16* g, u16* l) {
  __builtin_amdgcn_global_load_lds(
      (const __attribute__((address_space(1))) unsigned int*)g,
      (__attribute__((address_space(3))) unsigned int*)l, 16, 0, 0);
}

// ---------------- LayerNorm: fp32 in -> bf16 out (D=1024, one block per row) ----------------
__global__ __launch_bounds__(256) void ln_k(const float* __restrict__ x,
                                            const float* __restrict__ g,
                                            const float* __restrict__ b,
                                            u16* __restrict__ out) {
  const int row = blockIdx.x;
  const int t = threadIdx.x;
  const float4 v = *(const float4*)(x + (size_t)row * 1024 + t * 4);
  float s = v.x + v.y + v.z + v.w;
  float q = v.x * v.x + v.y * v.y + v.z * v.z + v.w * v.w;
#pragma unroll
  for (int m = 1; m < 64; m <<= 1) { s += __shfl_xor(s, m); q += __shfl_xor(q, m); }
  __shared__ float ss[4], qs[4];
  if ((t & 63) == 0) { ss[t >> 6] = s; qs[t >> 6] = q; }
  __syncthreads();
  s = ss[0] + ss[1] + ss[2] + ss[3];
  q = qs[0] + qs[1] + qs[2] + qs[3];
  const float mean = s * (1.0f / 1024.0f);
  const float var = q * (1.0f / 1024.0f) - mean * mean;
  const float rs = rsqrtf(var + 1e-6f);
  const float4 gv = *(const float4*)(g + t * 4);
  const float4 bv = *(const float4*)(b + t * 4);
  ushort4 o;
  o.x = f2bf((v.x - mean) * rs * gv.x + bv.x);
  o.y = f2bf((v.y - mean) * rs * gv.y + bv.y);
  o.z = f2bf((v.z - mean) * rs * gv.z + bv.z);
  o.w = f2bf((v.w - mean) * rs * gv.w + bv.w);
  *(ushort4*)(out + (size_t)row * 1024 + t * 4) = o;
}

// ---------------- weight transpose + cvt: src (K x N) f32 -> dst (N x K) bf16 ----------------
__global__ __launch_bounds__(256) void tcvt_k(const float* __restrict__ src,
                                              u16* __restrict__ dst, int K, int N) {
  __shared__ u16 tl[32][33];
  const int k0 = blockIdx.x * 32, n0 = blockIdx.y * 32;
  const int c = threadIdx.x & 31, r0 = threadIdx.x >> 5;
#pragma unroll
  for (int p = 0; p < 4; p++) {
    const int r = p * 8 + r0;
    tl[r][c] = f2bf(src[(size_t)(k0 + r) * N + n0 + c]);
  }
  __syncthreads();
#pragma unroll
  for (int p = 0; p < 4; p++) {
    const int r = p * 8 + r0;
    dst[(size_t)(n0 + r) * K + k0 + c] = tl[c][r];
  }
}

// ---------------- GEMM: C(MxN) = A(MxK,bf16) @ Bt(NxK,bf16)^T, fused epilogues ----------------
// 3-buffer K-loop with COUNTED vmcnt (T3+T4) + T2 chunk-XOR swizzle + T1 XCD block swizzle.
// EPI 0: out bf16 = acc + bias ; 1: gelu -> bf16 ; 2: f32 resid+gate*… ; 3: f32 += gate*…
template <int EPI, int TN>
__global__ __launch_bounds__(256) void gemm_bt(const u16* __restrict__ A,
                                               const u16* __restrict__ Bt,
                                               const float* __restrict__ bias,
                                               const float* __restrict__ resid,
                                               const float* __restrict__ gate,
                                               void* __restrict__ outv,
                                               int M, int N, int K) {
  constexpr int MI = (TN == 128) ? 4 : 2;    // m-frags per wave
  constexpr int WRS = (TN == 128) ? 64 : 32; // rows per wave
  constexpr int L = 2 + TN / 64;             // gloads per thread per stage
  __shared__ __align__(16) u16 lA[3][128 * 32];
  __shared__ __align__(16) u16 lB[3][TN * 32];
  const int tid = threadIdx.x;
  const int lane = tid & 63, wid = tid >> 6;
  const int l4 = lane >> 4, l15 = lane & 15;
  const int wr = (TN == 128) ? (wid >> 1) : wid;
  const int wc = (TN == 128) ? (wid & 1) : 0;
  // T1: XCD-aware swizzle (all grids have nwg % 8 == 0). Contiguous wf chunks share
  // the same B-panel (by) and land on one XCD's L2.
  const int nwgx = gridDim.x;
  const int f = blockIdx.x + nwgx * blockIdx.y;
  const int cpx = (nwgx * gridDim.y) >> 3;
  const int wf = (f & 7) * cpx + (f >> 3);
  const int mBase = (wf % nwgx) * 128;
  const int nBase = (wf / nwgx) * TN;

  f32x4 acc[MI][4];
#pragma unroll
  for (int i = 0; i < MI; i++)
#pragma unroll
    for (int j = 0; j < 4; j++)
#pragma unroll
      for (int e = 0; e < 4; e++) acc[i][j][e] = 0.f;

  const int sRow = tid >> 2;                                  // 0..63
  const int sCol = (((tid & 3) ^ ((sRow >> 1) & 3))) * 8;     // T2: source chunk pre-swizzle
  const int rsw = (l15 >> 1) & 3;                             // read-side slot XOR

#define STAGE(bufi, k0)                                                               \
  {                                                                                   \
    _Pragma("unroll") for (int p = 0; p < 2; p++)                                     \
        gload16(A + (size_t)(mBase + p * 64 + sRow) * K + (k0) + sCol,                \
                &lA[bufi][p * 2048 + wid * 512]);                                     \
    _Pragma("unroll") for (int p = 0; p < TN / 64; p++)                               \
        gload16(Bt + (size_t)(nBase + p * 64 + sRow) * K + (k0) + sCol,               \
                &lB[bufi][p * 2048 + wid * 512]);                                     \
  }

  const int nt = K >> 5;
  STAGE(0, 0);
  STAGE(1, 32);
  wait_vmcnt<L>();                    // buf0 retired; buf1's L in flight
  __builtin_amdgcn_s_barrier();
  __builtin_amdgcn_sched_barrier(0);

  int bsel = 0;
  for (int it = 0; it < nt; ++it) {
    bf16x8 af[MI], bfr[4];
#pragma unroll
    for (int mi = 0; mi < MI; mi++)
      af[mi] = *(const bf16x8*)(&lA[bsel][(wr * WRS + mi * 16 + l15) * 32 + (l4 ^ rsw) * 8]);
#pragma unroll
    for (int ni = 0; ni < 4; ni++)
      bfr[ni] = *(const bf16x8*)(&lB[bsel][(wc * 64 + ni * 16 + l15) * 32 + (l4 ^ rsw) * 8]);
    if (it + 2 < nt) {
      int b2 = bsel + 2; if (b2 >= 3) b2 -= 3;
      STAGE(b2, (it + 2) * 32);
    }
#pragma unroll
    for (int mi = 0; mi < MI; mi++)
#pragma unroll
      for (int ni = 0; ni < 4; ni++)
        acc[mi][ni] = __builtin_amdgcn_mfma_f32_16x16x32_bf16(af[mi], bfr[ni], acc[mi][ni], 0, 0, 0);
    if (it + 1 < nt) {
      asm volatile("s_waitcnt lgkmcnt(0)" ::: "memory");  // own ds_reads done (buffer recycle safety)
      __builtin_amdgcn_sched_barrier(0);
      if (it + 2 < nt) wait_vmcnt<L>();   // next buffer's loads retired; newest L stay in flight
      else wait_vmcnt<0>();               // tail: only next buffer's loads outstanding
      __builtin_amdgcn_s_barrier();
      __builtin_amdgcn_sched_barrier(0);
    }
    bsel = (bsel == 2) ? 0 : bsel + 1;
  }
#undef STAGE

  u16* obf = (u16*)outv;
  float* of = (float*)outv;
#pragma unroll
  for (int mi = 0; mi < MI; mi++) {
#pragma unroll
    for (int ni = 0; ni < 4; ni++) {
      const int row0 = mBase + wr * WRS + mi * 16 + l4 * 4;
      const int col = nBase + wc * 64 + ni * 16 + l15;
      const float bb = bias[col];
#pragma unroll
      for (int r = 0; r < 4; r++) {
        const float v = acc[mi][ni][r] + bb;
        const size_t idx = (size_t)(row0 + r) * N + col;
        if (EPI == 0) {
          obf[idx] = f2bf(v);
        } else if (EPI == 1) {
          const float ge = 0.5f * v * (1.0f + erff(v * 0.70710678118654752f));
          obf[idx] = f2bf(ge);
        } else if (EPI == 2) {
          of[idx] = resid[idx] + gate[col] * v;
        } else {
          of[idx] = of[idx] + gate[col] * v;
        }
      }
    }
  }
}

// ---------------- RoPE + head-layout: qkv(4096x3072 bf16) -> q_r/k_r (B,H,L,hd) bf16 ----------------
// q pre-scaled by (1/sqrt(hd)) * log2(e) so attention softmax runs in exp2 domain.
__global__ __launch_bounds__(256) void rope_k(const u16* __restrict__ qkv,
                                              u16* __restrict__ qr, u16* __restrict__ kr) {
  const int sel = blockIdx.y;  // 0 -> q, 1 -> k
  const int rid = blockIdx.x * 8 + (threadIdx.x >> 5);  // (b,h,t) row id, 0..65535
  const int i = threadIdx.x & 31;                       // pair index 0..31
  const int b = rid >> 15;
  const int h = (rid >> 11) & 15;
  const int t = rid & 2047;
  const u16* src = qkv + (size_t)(b * 2048 + t) * 3072 + sel * 1024 + h * 64 + 2 * i;
  const ushort2 uv = *(const ushort2*)src;
  const float x0 = bf2f(uv.x), x1 = bf2f(uv.y);
  const float inv = __expf(-(float)i * 0.28782313662425572f);  // ln(10000)/32
  float sn, cs;
  sincosf((float)t * inv, &sn, &cs);
  const float sc = sel ? 1.0f : 0.18033688011112042f;  // 0.125 * log2(e)
  ushort2 ov;
  ov.x = f2bf((x0 * cs - x1 * sn) * sc);
  ov.y = f2bf((x1 * cs + x0 * sn) * sc);
  *(ushort2*)((sel ? kr : qr) + (size_t)rid * 64 + 2 * i) = ov;
}

// ---------------- V layout: qkv cols 2048.. -> v_t (B,H,hd,L) bf16 (transposed) ----------------
__global__ __launch_bounds__(256) void vtrans_k(const u16* __restrict__ qkv, u16* __restrict__ vt) {
  __shared__ u16 tl[64][65];
  const int bh = blockIdx.x >> 5;
  const int t0 = (blockIdx.x & 31) * 64;
  const int b = bh >> 4, h = bh & 15;
  const int tid = threadIdx.x;
#pragma unroll
  for (int p = 0; p < 16; p++) {
    const int e = p * 256 + tid;
    const int tr = e >> 6, d = e & 63;
    tl[tr][d] = qkv[(size_t)(b * 2048 + t0 + tr) * 3072 + 2048 + h * 64 + d];
  }
  __syncthreads();
#pragma unroll
  for (int p = 0; p < 16; p++) {
    const int e = p * 256 + tid;
    const int dr = e >> 6, tc = e & 63;
    vt[(size_t)(bh * 64 + dr) * 2048 + t0 + tc] = tl[tc][dr];
  }
}

// ---------------- Flash attention: 32x32 MFMA, 8 waves = 2 KV-groups x 4 waves ----------------
// (Round-10 structure exactly, + T1 XCD swizzle: each XCD owns 4 complete heads so K/V
// lands in one XCD L2 instead of all eight.)
__global__ __launch_bounds__(512) void attn_k(const u16* __restrict__ q,
                                              const u16* __restrict__ k,
                                              const u16* __restrict__ vt,
                                              u16* __restrict__ o) {
  const int tid = threadIdx.x;
  const int grp = tid >> 8;            // KV-half
  const int wid = (tid >> 6) & 3;      // wave within group
  const int lane = tid & 63;
  const int h = lane >> 5, rq = lane & 31;
  // T1: nwg = 16 x 32 = 512; wf = (f&7)*64 + f>>3 -> XCD c gets heads 4c..4c+3 complete.
  const int f = blockIdx.x + (blockIdx.y << 4);
  const int wf = ((f & 7) << 6) + (f >> 3);
  const int qb = wf & 15;
  const int bh = wf >> 4;
  const int qrow0 = qb * 128 + wid * 32;

  __shared__ __align__(16) u16 kls[2][2][4096];   // [grp][buf] K tile [64 kv][64 d]
  __shared__ __align__(16) u16 vls[2][2][4096];   // [grp][buf] V^T tile [64 d][64 kv]
  __shared__ __align__(16) float alds[8][32];     // per-wave stat broadcast
  __shared__ __align__(16) float mls[4][32], lls[4][32];  // group1 -> group0 m,l

  // Q fragments: B-operand (col=q=rq, k=d = db*16 + 8h + j); same q-tile for both groups
  const u16* qbase = q + ((size_t)bh * 2048 + qrow0 + rq) * 64 + 8 * h;
  bf16x8 qf[4];
#pragma unroll
  for (int db = 0; db < 4; db++) qf[db] = *(const bf16x8*)(qbase + db * 16);

  float m0 = -1e30f, ls0 = 0.f;
  f32x16 oacc0, oacc1;
#pragma unroll
  for (int e = 0; e < 16; e++) { oacc0[e] = 0.f; oacc1[e] = 0.f; }

  const char* kg = (const char*)(k + (size_t)bh * 2048 * 64);   // K rows: 128 B
  const char* vg = (const char*)(vt + (size_t)bh * 64 * 2048);  // V^T rows: 4096 B
  const int t8 = tid & 255;
  const int sA = t8, sB = 256 + t8;
  const int rA = sA >> 3, cA = ((sA & 7) ^ (rA & 7)) << 4;
  const int rB = sB >> 3, cB = ((sB & 7) ^ (rB & 7)) << 4;
  u16* kgrp = &kls[grp][0][0];
  u16* vgrp = &vls[grp][0][0];
  u16* kd0 = kgrp + wid * 512;
  u16* kd1 = kgrp + 2048 + wid * 512;
  u16* vd0 = vgrp + wid * 512;
  u16* vd1 = vgrp + 2048 + wid * 512;
  const int kvbase = grp * 1024;

#define STAGE(bufi, kv0)                                                            \
  {                                                                                 \
    const int _o = (bufi)*4096;                                                     \
    gload16((const u16*)(kg + (size_t)((kv0) + rA) * 128 + cA), kd0 + _o);          \
    gload16((const u16*)(kg + (size_t)((kv0) + rB) * 128 + cB), kd1 + _o);          \
    gload16((const u16*)(vg + (size_t)rA * 4096 + (kv0)*2 + cA), vd0 + _o);         \
    gload16((const u16*)(vg + (size_t)rB * 4096 + (kv0)*2 + cB), vd1 + _o);         \
  }

  STAGE(0, kvbase);
  __syncthreads();

  float* AL = alds[tid >> 6];
  const int swz = (rq & 7) << 4;

// pack 8 consecutive-kv P values (regs B..B+7 of tile S) into the PV A-frag k-halves
#define PACK8(S, B, OUT)                                                            \
  {                                                                                 \
    unsigned wA = cvtpk(S[B + 0], S[B + 1]), wB_ = cvtpk(S[B + 2], S[B + 3]);       \
    unsigned wC = cvtpk(S[B + 4], S[B + 5]), wD = cvtpk(S[B + 6], S[B + 7]);        \
    unsigned xA = __shfl_xor(wA, 32), xB = __shfl_xor(wB_, 32);                     \
    unsigned xC = __shfl_xor(wC, 32), xD = __shfl_xor(wD, 32);                      \
    union { unsigned u[4]; bf16x8 v; } _m;                                          \
    _m.u[0] = h ? xC : wA; _m.u[1] = h ? xD : wB_;                                  \
    _m.u[2] = h ? wC : xA; _m.u[3] = h ? wD : xB;                                   \
    OUT = _m.v;                                                                     \
  }

  int buf = 0;
  for (int it = 0; it < 16; ++it) {
    if (it < 15) STAGE(buf ^ 1, kvbase + (it + 1) * 64);
    const char* K = (const char*)(kgrp + buf * 4096);
    const char* V = (const char*)(vgrp + buf * 4096);

    // ---- QK^T swapped: st0 = S^T[kv 0..31][q], st1 = S^T[kv 32..63][q]
    f32x16 st0, st1;
#pragma unroll
    for (int e = 0; e < 16; e++) { st0[e] = 0.f; st1[e] = 0.f; }
#pragma unroll
    for (int db = 0; db < 4; db++) {
      const int cb = db * 32;
      const bf16x8 ka0 = *(const bf16x8*)(K + rq * 128 + ((cb + 16 * h) ^ swz));
      const bf16x8 ka1 = *(const bf16x8*)(K + (32 + rq) * 128 + ((cb + 16 * h) ^ swz));
      st0 = __builtin_amdgcn_mfma_f32_32x32x16_bf16(ka0, qf[db], st0, 0, 0, 0);
      st1 = __builtin_amdgcn_mfma_f32_32x32x16_bf16(ka1, qf[db], st1, 0, 0, 0);
    }

    // ---- row max: in-lane tree + one lane^32 exchange (q = rq per lane)
    float t0 = fmaxf(fmaxf(st0[0], st0[1]), fmaxf(st0[2], st0[3]));
    float t1 = fmaxf(fmaxf(st0[4], st0[5]), fmaxf(st0[6], st0[7]));
    float t2 = fmaxf(fmaxf(st0[8], st0[9]), fmaxf(st0[10], st0[11]));
    float t3 = fmaxf(fmaxf(st0[12], st0[13]), fmaxf(st0[14], st0[15]));
    float t4 = fmaxf(fmaxf(st1[0], st1[1]), fmaxf(st1[2], st1[3]));
    float t5 = fmaxf(fmaxf(st1[4], st1[5]), fmaxf(st1[6], st1[7]));
    float t6 = fmaxf(fmaxf(st1[8], st1[9]), fmaxf(st1[10], st1[11]));
    float t7 = fmaxf(fmaxf(st1[12], st1[13]), fmaxf(st1[14], st1[15]));
    float pm = fmaxf(fmaxf(fmaxf(t0, t1), fmaxf(t2, t3)), fmaxf(fmaxf(t4, t5), fmaxf(t6, t7)));
    pm = fmaxf(pm, __shfl_xor(pm, 32));
    // defer-max (T13); THR = 8*log2e
    const bool need = !__all(pm <= m0 + 11.54f);
    float al0 = 1.0f;
    if (need) {
      const float mn = fmaxf(m0, pm);
      al0 = exp2a(m0 - mn);
      m0 = mn;
    }
    // ---- p = 2^(s - m)
#pragma unroll
    for (int e = 0; e < 16; e++) {
      st0[e] = exp2a(st0[e] - m0);
      st1[e] = exp2a(st1[e] - m0);
    }
    // ---- row sum (tree) + one exchange
    float u0 = (st0[0] + st0[1]) + (st0[2] + st0[3]);
    float u1 = (st0[4] + st0[5]) + (st0[6] + st0[7]);
    float u2 = (st0[8] + st0[9]) + (st0[10] + st0[11]);
    float u3 = (st0[12] + st0[13]) + (st0[14] + st0[15]);
    float u4 = (st1[0] + st1[1]) + (st1[2] + st1[3]);
    float u5 = (st1[4] + st1[5]) + (st1[6] + st1[7]);
    float u6 = (st1[8] + st1[9]) + (st1[10] + st1[11]);
    float u7 = (st1[12] + st1[13]) + (st1[14] + st1[15]);
    float ps = ((u0 + u1) + (u2 + u3)) + ((u4 + u5) + (u6 + u7));
    ps += __shfl_xor(ps, 32);
    ls0 = ls0 * al0 + ps;

    // ---- rescale O (rare): broadcast al[q] lane-domain -> reg-domain via 128B LDS
    if (need) {
      if (lane < 32) AL[rq] = al0;
      const f32x4 a0 = *(const f32x4*)((const char*)AL + 16 * h);
      const f32x4 a1 = *(const f32x4*)((const char*)AL + 32 + 16 * h);
      const f32x4 a2 = *(const f32x4*)((const char*)AL + 64 + 16 * h);
      const f32x4 a3 = *(const f32x4*)((const char*)AL + 96 + 16 * h);
#pragma unroll
      for (int r = 0; r < 4; r++) {
        oacc0[r] *= a0[r]; oacc0[4 + r] *= a1[r]; oacc0[8 + r] *= a2[r]; oacc0[12 + r] *= a3[r];
        oacc1[r] *= a0[r]; oacc1[4 + r] *= a1[r]; oacc1[8 + r] *= a2[r]; oacc1[12 + r] *= a3[r];
      }
    }

    // ---- P -> A-frags in-register (no LDS): pa[kb] covers kv = kb*16 .. +15
    bf16x8 pa[4];
    PACK8(st0, 0, pa[0]);
    PACK8(st0, 8, pa[1]);
    PACK8(st1, 0, pa[2]);
    PACK8(st1, 8, pa[3]);

    // ---- PV: oacc0 = O[q][d 0..31], oacc1 = O[q][d 32..63]
#pragma unroll
    for (int kb = 0; kb < 4; kb++) {
      const int cb = kb * 32;
      const bf16x8 vb0 = *(const bf16x8*)(V + rq * 128 + ((cb + 16 * h) ^ swz));
      const bf16x8 vb1 = *(const bf16x8*)(V + (32 + rq) * 128 + ((cb + 16 * h) ^ swz));
      oacc0 = __builtin_amdgcn_mfma_f32_32x32x16_bf16(pa[kb], vb0, oacc0, 0, 0, 0);
      oacc1 = __builtin_amdgcn_mfma_f32_32x32x16_bf16(pa[kb], vb1, oacc1, 0, 0, 0);
    }
    __syncthreads();  // drains vmcnt(0): staged tile ready; old buf free
    buf ^= 1;
  }
#undef STAGE
#undef PACK8

  // ---- cross-group combine. comb aliases kls (32KB, dead after final barrier).
  float* comb = (float*)&kls[0][0][0];  // [wid][q 32][d 64] f32
  if (grp == 1) {
    if (lane < 32) { mls[wid][rq] = m0; lls[wid][rq] = ls0; }
    float* cw = comb + wid * 2048;
#pragma unroll
    for (int r = 0; r < 16; r++) {
      const int ql = (r & 3) + 8 * (r >> 2) + 4 * h;
      cw[ql * 64 + rq] = oacc0[r];
      cw[ql * 64 + 32 + rq] = oacc1[r];
    }
  }
  __syncthreads();
  if (grp == 0) {
    const float mb = mls[wid][rq], lb = lls[wid][rq];
    const float M = fmaxf(m0, mb);
    const float sa = exp2a(m0 - M), sb = exp2a(mb - M);
    const float linv = 1.0f / (ls0 * sa + lb * sb);
    if (lane < 32) { AL[rq] = sa * linv; mls[wid][rq] = sb * linv; }
    asm volatile("s_waitcnt lgkmcnt(0)" ::: "memory");
    f32x4 fa[4], fb[4];
#pragma unroll
    for (int g = 0; g < 4; g++) {
      fa[g] = *(const f32x4*)((const char*)AL + g * 32 + 16 * h);
      fb[g] = *(const f32x4*)((const char*)&mls[wid][0] + g * 32 + 16 * h);
    }
    const float* cw = comb + wid * 2048;
    const int b = bh >> 4, hh = bh & 15;
#pragma unroll
    for (int r = 0; r < 16; r++) {
      const int ql = (r & 3) + 8 * (r >> 2) + 4 * h;
      const float A = fa[r >> 2][r & 3], B = fb[r >> 2][r & 3];
      u16* orow = o + ((size_t)b * 2048 + qrow0 + ql) * 1024 + hh * 64;
      orow[rq] = f2bf(oacc0[r] * A + cw[ql * 64 + rq] * B);
      orow[32 + rq] = f2bf(oacc1[r] * A + cw[ql * 64 + 32 + rq] * B);
    }
  }
}

extern "C" void kernel_launch(void* const* d_in, const int* in_sizes, int n_in,
                              void* d_out, int out_size, void* d_ws, size_t ws_size,
                              hipStream_t stream) {
  (void)in_sizes; (void)n_in; (void)out_size; (void)ws_size;
  const float* x     = (const float*)d_in[0];
  const float* ln1_g = (const float*)d_in[1];
  const float* ln1_b = (const float*)d_in[2];
  const float* wq    = (const float*)d_in[3];
  const float* bq    = (const float*)d_in[4];
  const float* wk    = (const float*)d_in[5];
  const float* bk    = (const float*)d_in[6];
  const float* wv    = (const float*)d_in[7];
  const float* bv    = (const float*)d_in[8];
  const float* wo    = (const float*)d_in[9];
  const float* bo    = (const float*)d_in[10];
  const float* ln2_g = (const float*)d_in[11];
  const float* ln2_b = (const float*)d_in[12];
  const float* w1    = (const float*)d_in[13];
  const float* b1    = (const float*)d_in[14];
  const float* w2    = (const float*)d_in[15];
  const float* b2    = (const float*)d_in[16];
  const float* gmsa  = (const float*)d_in[17];
  const float* gmlp  = (const float*)d_in[18];
  float* out = (float*)d_out;

  char* w = (char*)d_ws;
  auto alloc = [&](size_t bytes) {
    char* p = w;
    w += (bytes + 255) & ~(size_t)255;
    return p;
  };
  u16* h1     = (u16*)alloc(4096UL * 1024 * 2);
  u16* wqkv_t = (u16*)alloc(3072UL * 1024 * 2);
  u16* wo_t   = (u16*)alloc(1024UL * 1024 * 2);
  u16* w1_t   = (u16*)alloc(4096UL * 1024 * 2);
  u16* w2_t   = (u16*)alloc(1024UL * 4096 * 2);
  float* bqkv = (float*)alloc(3072UL * 4);
  u16* qkv    = (u16*)alloc(4096UL * 3072 * 2);
  u16* q_r    = (u16*)alloc(65536UL * 64 * 2);
  u16* k_r    = (u16*)alloc(65536UL * 64 * 2);
  u16* v_t    = (u16*)alloc(65536UL * 64 * 2);
  u16* o_at   = (u16*)alloc(4096UL * 1024 * 2);
  u16* h2     = (u16*)alloc(4096UL * 1024 * 2);
  u16* g1     = (u16*)alloc(4096UL * 4096 * 2);

  // weights -> bf16, transposed to (N x K); qkv packed [wq; wk; wv]
  tcvt_k<<<dim3(32, 32), 256, 0, stream>>>(wq, wqkv_t, 1024, 1024);
  tcvt_k<<<dim3(32, 32), 256, 0, stream>>>(wk, wqkv_t + 1024 * 1024, 1024, 1024);
  tcvt_k<<<dim3(32, 32), 256, 0, stream>>>(wv, wqkv_t + 2048 * 1024, 1024, 1024);
  tcvt_k<<<dim3(32, 32), 256, 0, stream>>>(wo, wo_t, 1024, 1024);
  tcvt_k<<<dim3(32, 128), 256, 0, stream>>>(w1, w1_t, 1024, 4096);
  tcvt_k<<<dim3(128, 32), 256, 0, stream>>>(w2, w2_t, 4096, 1024);
  hipMemcpyAsync(bqkv,        bq, 1024 * sizeof(float), hipMemcpyDeviceToDevice, stream);
  hipMemcpyAsync(bqkv + 1024, bk, 1024 * sizeof(float), hipMemcpyDeviceToDevice, stream);
  hipMemcpyAsync(bqkv + 2048, bv, 1024 * sizeof(float), hipMemcpyDeviceToDevice, stream);

  // attention branch
  ln_k<<<4096, 256, 0, stream>>>(x, ln1_g, ln1_b, h1);
  gemm_bt<0, 128><<<dim3(32, 24), 256, 0, stream>>>(h1, wqkv_t, bqkv, nullptr, nullptr, qkv, 4096, 3072, 1024);
  rope_k<<<dim3(8192, 2), 256, 0, stream>>>(qkv, q_r, k_r);
  vtrans_k<<<1024, 256, 0, stream>>>(qkv, v_t);
  attn_k<<<dim3(16, 32), 512, 0, stream>>>(q_r, k_r, v_t, o_at);
  // x1 = x + gate_msa * (o @ wo + bo)  -> written to d_out (fp32)
  gemm_bt<2, 64><<<dim3(32, 16), 256, 0, stream>>>(o_at, wo_t, bo, x, gmsa, out, 4096, 1024, 1024);

  // MLP branch (accumulates into d_out)
  ln_k<<<4096, 256, 0, stream>>>(out, ln2_g, ln2_b, h2);
  gemm_bt<1, 128><<<dim3(32, 32), 256, 0, stream>>>(h2, w1_t, b1, nullptr, nullptr, g1, 4096, 4096, 1024);
  gemm_bt<3, 64><<<dim3(32, 16), 256, 0, stream>>>(g1, w2_t, b2, nullptr, gmlp, out, 4096, 1024, 4096);
}

// Round 16
// 282.966 us; speedup vs baseline: 1.0391x; 1.0391x over previous
//
#include <hip/hip_runtime.h>

typedef unsigned short u16;
typedef __attribute__((ext_vector_type(4))) float f32x4;
typedef __attribute__((ext_vector_type(16))) float f32x16;
typedef __attribute__((ext_vector_type(8))) short bf16x8;

#define DEV static __device__ __forceinline__

DEV float bf2f(u16 u) { unsigned int i = ((unsigned int)u) << 16; return __builtin_bit_cast(float, i); }
DEV u16 f2bf(float f) {
  unsigned int x = __builtin_bit_cast(unsigned int, f);
  x += 0x7fffu + ((x >> 16) & 1u);
  return (u16)(x >> 16);
}

// HW pack: one instr for 2 f32 -> 2 bf16 (RNE). No builtin on gfx950 (T12 recipe).
DEV unsigned cvtpk(float lo, float hi) {
  unsigned r;
  asm("v_cvt_pk_bf16_f32 %0, %1, %2" : "=v"(r) : "v"(lo), "v"(hi));
  return r;
}
// Raw 2^x (softmax kept in log2 domain; Q pre-scaled by log2e).
DEV float exp2a(float x) {
  float r;
  asm("v_exp_f32 %0, %1" : "=v"(r) : "v"(x));
  return r;
}

template <int N>
DEV void wait_vmcnt() {
  if constexpr (N == 0) asm volatile("s_waitcnt vmcnt(0)" ::: "memory");
  else if constexpr (N == 3) asm volatile("s_waitcnt vmcnt(3)" ::: "memory");
  else if constexpr (N == 4) asm volatile("s_waitcnt vmcnt(4)" ::: "memory");
  else static_assert(N == 0, "unsupported vmcnt");
}

DEV void gload16(const u16* g, u16* l) {
  __builtin_amdgcn_global_load_lds(
      (const __attribute__((address_space(1))) unsigned int*)g,
      (__attribute__((address_space(3))) unsigned int*)l, 16, 0, 0);
}

// ---------------- LayerNorm: fp32 in -> bf16 out (D=1024, one block per row) ----------------
__global__ __launch_bounds__(256) void ln_k(const float* __restrict__ x,
                                            const float* __restrict__ g,
                                            const float* __restrict__ b,
                                            u16* __restrict__ out) {
  const int row = blockIdx.x;
  const int t = threadIdx.x;
  const float4 v = *(const float4*)(x + (size_t)row * 1024 + t * 4);
  float s = v.x + v.y + v.z + v.w;
  float q = v.x * v.x + v.y * v.y + v.z * v.z + v.w * v.w;
#pragma unroll
  for (int m = 1; m < 64; m <<= 1) { s += __shfl_xor(s, m); q += __shfl_xor(q, m); }
  __shared__ float ss[4], qs[4];
  if ((t & 63) == 0) { ss[t >> 6] = s; qs[t >> 6] = q; }
  __syncthreads();
  s = ss[0] + ss[1] + ss[2] + ss[3];
  q = qs[0] + qs[1] + qs[2] + qs[3];
  const float mean = s * (1.0f / 1024.0f);
  const float var = q * (1.0f / 1024.0f) - mean * mean;
  const float rs = rsqrtf(var + 1e-6f);
  const float4 gv = *(const float4*)(g + t * 4);
  const float4 bv = *(const float4*)(b + t * 4);
  ushort4 o;
  o.x = f2bf((v.x - mean) * rs * gv.x + bv.x);
  o.y = f2bf((v.y - mean) * rs * gv.y + bv.y);
  o.z = f2bf((v.z - mean) * rs * gv.z + bv.z);
  o.w = f2bf((v.w - mean) * rs * gv.w + bv.w);
  *(ushort4*)(out + (size_t)row * 1024 + t * 4) = o;
}

// ---------------- weight transpose + cvt: src (K x N) f32 -> dst (N x K) bf16 ----------------
__global__ __launch_bounds__(256) void tcvt_k(const float* __restrict__ src,
                                              u16* __restrict__ dst, int K, int N) {
  __shared__ u16 tl[32][33];
  const int k0 = blockIdx.x * 32, n0 = blockIdx.y * 32;
  const int c = threadIdx.x & 31, r0 = threadIdx.x >> 5;
#pragma unroll
  for (int p = 0; p < 4; p++) {
    const int r = p * 8 + r0;
    tl[r][c] = f2bf(src[(size_t)(k0 + r) * N + n0 + c]);
  }
  __syncthreads();
#pragma unroll
  for (int p = 0; p < 4; p++) {
    const int r = p * 8 + r0;
    dst[(size_t)(n0 + r) * K + k0 + c] = tl[c][r];
  }
}

// ---------------- GEMM: C(MxN) = A(MxK,bf16) @ Bt(NxK,bf16)^T, fused epilogues ----------------
// 3-buffer K-loop with COUNTED vmcnt (T3+T4) + T2 chunk-XOR swizzle (r10 config, best known).
// No T1 block swizzle: r15 A/B showed it HURTS here (default x-major order already gives
// per-XCD B-panel sharing; remap forced full-A re-fetch per XCD; all panels L3-fit anyway).
// EPI 0: out bf16 = acc + bias ; 1: gelu -> bf16 ; 2: f32 resid+gate*… ; 3: f32 += gate*…
template <int EPI, int TN>
__global__ __launch_bounds__(256) void gemm_bt(const u16* __restrict__ A,
                                               const u16* __restrict__ Bt,
                                               const float* __restrict__ bias,
                                               const float* __restrict__ resid,
                                               const float* __restrict__ gate,
                                               void* __restrict__ outv,
                                               int M, int N, int K) {
  constexpr int MI = (TN == 128) ? 4 : 2;    // m-frags per wave
  constexpr int WRS = (TN == 128) ? 64 : 32; // rows per wave
  constexpr int L = 2 + TN / 64;             // gloads per thread per stage
  __shared__ __align__(16) u16 lA[3][128 * 32];
  __shared__ __align__(16) u16 lB[3][TN * 32];
  const int tid = threadIdx.x;
  const int lane = tid & 63, wid = tid >> 6;
  const int l4 = lane >> 4, l15 = lane & 15;
  const int wr = (TN == 128) ? (wid >> 1) : wid;
  const int wc = (TN == 128) ? (wid & 1) : 0;
  const int mBase = blockIdx.x * 128;
  const int nBase = blockIdx.y * TN;

  f32x4 acc[MI][4];
#pragma unroll
  for (int i = 0; i < MI; i++)
#pragma unroll
    for (int j = 0; j < 4; j++)
#pragma unroll
      for (int e = 0; e < 4; e++) acc[i][j][e] = 0.f;

  const int sRow = tid >> 2;                                  // 0..63
  const int sCol = (((tid & 3) ^ ((sRow >> 1) & 3))) * 8;     // T2: source chunk pre-swizzle
  const int rsw = (l15 >> 1) & 3;                             // read-side slot XOR

#define STAGE(bufi, k0)                                                               \
  {                                                                                   \
    _Pragma("unroll") for (int p = 0; p < 2; p++)                                     \
        gload16(A + (size_t)(mBase + p * 64 + sRow) * K + (k0) + sCol,                \
                &lA[bufi][p * 2048 + wid * 512]);                                     \
    _Pragma("unroll") for (int p = 0; p < TN / 64; p++)                               \
        gload16(Bt + (size_t)(nBase + p * 64 + sRow) * K + (k0) + sCol,               \
                &lB[bufi][p * 2048 + wid * 512]);                                     \
  }

  const int nt = K >> 5;
  STAGE(0, 0);
  STAGE(1, 32);
  wait_vmcnt<L>();                    // buf0 retired; buf1's L in flight
  __builtin_amdgcn_s_barrier();
  __builtin_amdgcn_sched_barrier(0);

  int bsel = 0;
  for (int it = 0; it < nt; ++it) {
    bf16x8 af[MI], bfr[4];
#pragma unroll
    for (int mi = 0; mi < MI; mi++)
      af[mi] = *(const bf16x8*)(&lA[bsel][(wr * WRS + mi * 16 + l15) * 32 + (l4 ^ rsw) * 8]);
#pragma unroll
    for (int ni = 0; ni < 4; ni++)
      bfr[ni] = *(const bf16x8*)(&lB[bsel][(wc * 64 + ni * 16 + l15) * 32 + (l4 ^ rsw) * 8]);
    if (it + 2 < nt) {
      int b2 = bsel + 2; if (b2 >= 3) b2 -= 3;
      STAGE(b2, (it + 2) * 32);
    }
#pragma unroll
    for (int mi = 0; mi < MI; mi++)
#pragma unroll
      for (int ni = 0; ni < 4; ni++)
        acc[mi][ni] = __builtin_amdgcn_mfma_f32_16x16x32_bf16(af[mi], bfr[ni], acc[mi][ni], 0, 0, 0);
    if (it + 1 < nt) {
      asm volatile("s_waitcnt lgkmcnt(0)" ::: "memory");  // own ds_reads done (buffer recycle safety)
      __builtin_amdgcn_sched_barrier(0);
      if (it + 2 < nt) wait_vmcnt<L>();   // next buffer's loads retired; newest L stay in flight
      else wait_vmcnt<0>();               // tail: only next buffer's loads outstanding
      __builtin_amdgcn_s_barrier();
      __builtin_amdgcn_sched_barrier(0);
    }
    bsel = (bsel == 2) ? 0 : bsel + 1;
  }
#undef STAGE

  u16* obf = (u16*)outv;
  float* of = (float*)outv;
#pragma unroll
  for (int mi = 0; mi < MI; mi++) {
#pragma unroll
    for (int ni = 0; ni < 4; ni++) {
      const int row0 = mBase + wr * WRS + mi * 16 + l4 * 4;
      const int col = nBase + wc * 64 + ni * 16 + l15;
      const float bb = bias[col];
#pragma unroll
      for (int r = 0; r < 4; r++) {
        const float v = acc[mi][ni][r] + bb;
        const size_t idx = (size_t)(row0 + r) * N + col;
        if (EPI == 0) {
          obf[idx] = f2bf(v);
        } else if (EPI == 1) {
          const float ge = 0.5f * v * (1.0f + erff(v * 0.70710678118654752f));
          obf[idx] = f2bf(ge);
        } else if (EPI == 2) {
          of[idx] = resid[idx] + gate[col] * v;
        } else {
          of[idx] = of[idx] + gate[col] * v;
        }
      }
    }
  }
}

// ---------------- RoPE + head-layout: qkv(4096x3072 bf16) -> q_r/k_r (B,H,L,hd) bf16 ----------------
// q pre-scaled by (1/sqrt(hd)) * log2(e) so attention softmax runs in exp2 domain.
__global__ __launch_bounds__(256) void rope_k(const u16* __restrict__ qkv,
                                              u16* __restrict__ qr, u16* __restrict__ kr) {
  const int sel = blockIdx.y;  // 0 -> q, 1 -> k
  const int rid = blockIdx.x * 8 + (threadIdx.x >> 5);  // (b,h,t) row id, 0..65535
  const int i = threadIdx.x & 31;                       // pair index 0..31
  const int b = rid >> 15;
  const int h = (rid >> 11) & 15;
  const int t = rid & 2047;
  const u16* src = qkv + (size_t)(b * 2048 + t) * 3072 + sel * 1024 + h * 64 + 2 * i;
  const ushort2 uv = *(const ushort2*)src;
  const float x0 = bf2f(uv.x), x1 = bf2f(uv.y);
  const float inv = __expf(-(float)i * 0.28782313662425572f);  // ln(10000)/32
  float sn, cs;
  sincosf((float)t * inv, &sn, &cs);
  const float sc = sel ? 1.0f : 0.18033688011112042f;  // 0.125 * log2(e)
  ushort2 ov;
  ov.x = f2bf((x0 * cs - x1 * sn) * sc);
  ov.y = f2bf((x1 * cs + x0 * sn) * sc);
  *(ushort2*)((sel ? kr : qr) + (size_t)rid * 64 + 2 * i) = ov;
}

// ---------------- V layout: qkv cols 2048.. -> v_t (B,H,hd,L) bf16 (transposed) ----------------
__global__ __launch_bounds__(256) void vtrans_k(const u16* __restrict__ qkv, u16* __restrict__ vt) {
  __shared__ u16 tl[64][65];
  const int bh = blockIdx.x >> 5;
  const int t0 = (blockIdx.x & 31) * 64;
  const int b = bh >> 4, h = bh & 15;
  const int tid = threadIdx.x;
#pragma unroll
  for (int p = 0; p < 16; p++) {
    const int e = p * 256 + tid;
    const int tr = e >> 6, d = e & 63;
    tl[tr][d] = qkv[(size_t)(b * 2048 + t0 + tr) * 3072 + 2048 + h * 64 + d];
  }
  __syncthreads();
#pragma unroll
  for (int p = 0; p < 16; p++) {
    const int e = p * 256 + tid;
    const int dr = e >> 6, tc = e & 63;
    vt[(size_t)(bh * 64 + dr) * 2048 + t0 + tc] = tl[tc][dr];
  }
}

// ---------------- Flash attention: 32x32 MFMA, 8 waves = 2 KV-groups x 4 waves ----------------
// (Round-10 structure + T1 XCD swizzle kept from r15: attn dropped out of top-5 with it.
// Each XCD owns 4 complete heads so K/V lands in one XCD L2 instead of all eight.)
__global__ __launch_bounds__(512) void attn_k(const u16* __restrict__ q,
                                              const u16* __restrict__ k,
                                              const u16* __restrict__ vt,
                                              u16* __restrict__ o) {
  const int tid = threadIdx.x;
  const int grp = tid >> 8;            // KV-half
  const int wid = (tid >> 6) & 3;      // wave within group
  const int lane = tid & 63;
  const int h = lane >> 5, rq = lane & 31;
  // T1: nwg = 16 x 32 = 512; wf = (f&7)*64 + f>>3 -> XCD c gets heads 4c..4c+3 complete.
  const int f = blockIdx.x + (blockIdx.y << 4);
  const int wf = ((f & 7) << 6) + (f >> 3);
  const int qb = wf & 15;
  const int bh = wf >> 4;
  const int qrow0 = qb * 128 + wid * 32;

  __shared__ __align__(16) u16 kls[2][2][4096];   // [grp][buf] K tile [64 kv][64 d]
  __shared__ __align__(16) u16 vls[2][2][4096];   // [grp][buf] V^T tile [64 d][64 kv]
  __shared__ __align__(16) float alds[8][32];     // per-wave stat broadcast
  __shared__ __align__(16) float mls[4][32], lls[4][32];  // group1 -> group0 m,l

  // Q fragments: B-operand (col=q=rq, k=d = db*16 + 8h + j); same q-tile for both groups
  const u16* qbase = q + ((size_t)bh * 2048 + qrow0 + rq) * 64 + 8 * h;
  bf16x8 qf[4];
#pragma unroll
  for (int db = 0; db < 4; db++) qf[db] = *(const bf16x8*)(qbase + db * 16);

  float m0 = -1e30f, ls0 = 0.f;
  f32x16 oacc0, oacc1;
#pragma unroll
  for (int e = 0; e < 16; e++) { oacc0[e] = 0.f; oacc1[e] = 0.f; }

  const char* kg = (const char*)(k + (size_t)bh * 2048 * 64);   // K rows: 128 B
  const char* vg = (const char*)(vt + (size_t)bh * 64 * 2048);  // V^T rows: 4096 B
  const int t8 = tid & 255;
  const int sA = t8, sB = 256 + t8;
  const int rA = sA >> 3, cA = ((sA & 7) ^ (rA & 7)) << 4;
  const int rB = sB >> 3, cB = ((sB & 7) ^ (rB & 7)) << 4;
  u16* kgrp = &kls[grp][0][0];
  u16* vgrp = &vls[grp][0][0];
  u16* kd0 = kgrp + wid * 512;
  u16* kd1 = kgrp + 2048 + wid * 512;
  u16* vd0 = vgrp + wid * 512;
  u16* vd1 = vgrp + 2048 + wid * 512;
  const int kvbase = grp * 1024;

#define STAGE(bufi, kv0)                                                            \
  {                                                                                 \
    const int _o = (bufi)*4096;                                                     \
    gload16((const u16*)(kg + (size_t)((kv0) + rA) * 128 + cA), kd0 + _o);          \
    gload16((const u16*)(kg + (size_t)((kv0) + rB) * 128 + cB), kd1 + _o);          \
    gload16((const u16*)(vg + (size_t)rA * 4096 + (kv0)*2 + cA), vd0 + _o);         \
    gload16((const u16*)(vg + (size_t)rB * 4096 + (kv0)*2 + cB), vd1 + _o);         \
  }

  STAGE(0, kvbase);
  __syncthreads();

  float* AL = alds[tid >> 6];
  const int swz = (rq & 7) << 4;

// pack 8 consecutive-kv P values (regs B..B+7 of tile S) into the PV A-frag k-halves
#define PACK8(S, B, OUT)                                                            \
  {                                                                                 \
    unsigned wA = cvtpk(S[B + 0], S[B + 1]), wB_ = cvtpk(S[B + 2], S[B + 3]);       \
    unsigned wC = cvtpk(S[B + 4], S[B + 5]), wD = cvtpk(S[B + 6], S[B + 7]);        \
    unsigned xA = __shfl_xor(wA, 32), xB = __shfl_xor(wB_, 32);                     \
    unsigned xC = __shfl_xor(wC, 32), xD = __shfl_xor(wD, 32);                      \
    union { unsigned u[4]; bf16x8 v; } _m;                                          \
    _m.u[0] = h ? xC : wA; _m.u[1] = h ? xD : wB_;                                  \
    _m.u[2] = h ? wC : xA; _m.u[3] = h ? wD : xB;                                   \
    OUT = _m.v;                                                                     \
  }

  int buf = 0;
  for (int it = 0; it < 16; ++it) {
    if (it < 15) STAGE(buf ^ 1, kvbase + (it + 1) * 64);
    const char* K = (const char*)(kgrp + buf * 4096);
    const char* V = (const char*)(vgrp + buf * 4096);

    // ---- QK^T swapped: st0 = S^T[kv 0..31][q], st1 = S^T[kv 32..63][q]
    f32x16 st0, st1;
#pragma unroll
    for (int e = 0; e < 16; e++) { st0[e] = 0.f; st1[e] = 0.f; }
#pragma unroll
    for (int db = 0; db < 4; db++) {
      const int cb = db * 32;
      const bf16x8 ka0 = *(const bf16x8*)(K + rq * 128 + ((cb + 16 * h) ^ swz));
      const bf16x8 ka1 = *(const bf16x8*)(K + (32 + rq) * 128 + ((cb + 16 * h) ^ swz));
      st0 = __builtin_amdgcn_mfma_f32_32x32x16_bf16(ka0, qf[db], st0, 0, 0, 0);
      st1 = __builtin_amdgcn_mfma_f32_32x32x16_bf16(ka1, qf[db], st1, 0, 0, 0);
    }

    // ---- row max: in-lane tree + one lane^32 exchange (q = rq per lane)
    float t0 = fmaxf(fmaxf(st0[0], st0[1]), fmaxf(st0[2], st0[3]));
    float t1 = fmaxf(fmaxf(st0[4], st0[5]), fmaxf(st0[6], st0[7]));
    float t2 = fmaxf(fmaxf(st0[8], st0[9]), fmaxf(st0[10], st0[11]));
    float t3 = fmaxf(fmaxf(st0[12], st0[13]), fmaxf(st0[14], st0[15]));
    float t4 = fmaxf(fmaxf(st1[0], st1[1]), fmaxf(st1[2], st1[3]));
    float t5 = fmaxf(fmaxf(st1[4], st1[5]), fmaxf(st1[6], st1[7]));
    float t6 = fmaxf(fmaxf(st1[8], st1[9]), fmaxf(st1[10], st1[11]));
    float t7 = fmaxf(fmaxf(st1[12], st1[13]), fmaxf(st1[14], st1[15]));
    float pm = fmaxf(fmaxf(fmaxf(t0, t1), fmaxf(t2, t3)), fmaxf(fmaxf(t4, t5), fmaxf(t6, t7)));
    pm = fmaxf(pm, __shfl_xor(pm, 32));
    // defer-max (T13); THR = 8*log2e
    const bool need = !__all(pm <= m0 + 11.54f);
    float al0 = 1.0f;
    if (need) {
      const float mn = fmaxf(m0, pm);
      al0 = exp2a(m0 - mn);
      m0 = mn;
    }
    // ---- p = 2^(s - m)
#pragma unroll
    for (int e = 0; e < 16; e++) {
      st0[e] = exp2a(st0[e] - m0);
      st1[e] = exp2a(st1[e] - m0);
    }
    // ---- row sum (tree) + one exchange
    float u0 = (st0[0] + st0[1]) + (st0[2] + st0[3]);
    float u1 = (st0[4] + st0[5]) + (st0[6] + st0[7]);
    float u2 = (st0[8] + st0[9]) + (st0[10] + st0[11]);
    float u3 = (st0[12] + st0[13]) + (st0[14] + st0[15]);
    float u4 = (st1[0] + st1[1]) + (st1[2] + st1[3]);
    float u5 = (st1[4] + st1[5]) + (st1[6] + st1[7]);
    float u6 = (st1[8] + st1[9]) + (st1[10] + st1[11]);
    float u7 = (st1[12] + st1[13]) + (st1[14] + st1[15]);
    float ps = ((u0 + u1) + (u2 + u3)) + ((u4 + u5) + (u6 + u7));
    ps += __shfl_xor(ps, 32);
    ls0 = ls0 * al0 + ps;

    // ---- rescale O (rare): broadcast al[q] lane-domain -> reg-domain via 128B LDS
    if (need) {
      if (lane < 32) AL[rq] = al0;
      const f32x4 a0 = *(const f32x4*)((const char*)AL + 16 * h);
      const f32x4 a1 = *(const f32x4*)((const char*)AL + 32 + 16 * h);
      const f32x4 a2 = *(const f32x4*)((const char*)AL + 64 + 16 * h);
      const f32x4 a3 = *(const f32x4*)((const char*)AL + 96 + 16 * h);
#pragma unroll
      for (int r = 0; r < 4; r++) {
        oacc0[r] *= a0[r]; oacc0[4 + r] *= a1[r]; oacc0[8 + r] *= a2[r]; oacc0[12 + r] *= a3[r];
        oacc1[r] *= a0[r]; oacc1[4 + r] *= a1[r]; oacc1[8 + r] *= a2[r]; oacc1[12 + r] *= a3[r];
      }
    }

    // ---- P -> A-frags in-register (no LDS): pa[kb] covers kv = kb*16 .. +15
    bf16x8 pa[4];
    PACK8(st0, 0, pa[0]);
    PACK8(st0, 8, pa[1]);
    PACK8(st1, 0, pa[2]);
    PACK8(st1, 8, pa[3]);

    // ---- PV: oacc0 = O[q][d 0..31], oacc1 = O[q][d 32..63]
#pragma unroll
    for (int kb = 0; kb < 4; kb++) {
      const int cb = kb * 32;
      const bf16x8 vb0 = *(const bf16x8*)(V + rq * 128 + ((cb + 16 * h) ^ swz));
      const bf16x8 vb1 = *(const bf16x8*)(V + (32 + rq) * 128 + ((cb + 16 * h) ^ swz));
      oacc0 = __builtin_amdgcn_mfma_f32_32x32x16_bf16(pa[kb], vb0, oacc0, 0, 0, 0);
      oacc1 = __builtin_amdgcn_mfma_f32_32x32x16_bf16(pa[kb], vb1, oacc1, 0, 0, 0);
    }
    __syncthreads();  // drains vmcnt(0): staged tile ready; old buf free
    buf ^= 1;
  }
#undef STAGE
#undef PACK8

  // ---- cross-group combine. comb aliases kls (32KB, dead after final barrier).
  float* comb = (float*)&kls[0][0][0];  // [wid][q 32][d 64] f32
  if (grp == 1) {
    if (lane < 32) { mls[wid][rq] = m0; lls[wid][rq] = ls0; }
    float* cw = comb + wid * 2048;
#pragma unroll
    for (int r = 0; r < 16; r++) {
      const int ql = (r & 3) + 8 * (r >> 2) + 4 * h;
      cw[ql * 64 + rq] = oacc0[r];
      cw[ql * 64 + 32 + rq] = oacc1[r];
    }
  }
  __syncthreads();
  if (grp == 0) {
    const float mb = mls[wid][rq], lb = lls[wid][rq];
    const float M = fmaxf(m0, mb);
    const float sa = exp2a(m0 - M), sb = exp2a(mb - M);
    const float linv = 1.0f / (ls0 * sa + lb * sb);
    if (lane < 32) { AL[rq] = sa * linv; mls[wid][rq] = sb * linv; }
    asm volatile("s_waitcnt lgkmcnt(0)" ::: "memory");
    f32x4 fa[4], fb[4];
#pragma unroll
    for (int g = 0; g < 4; g++) {
      fa[g] = *(const f32x4*)((const char*)AL + g * 32 + 16 * h);
      fb[g] = *(const f32x4*)((const char*)&mls[wid][0] + g * 32 + 16 * h);
    }
    const float* cw = comb + wid * 2048;
    const int b = bh >> 4, hh = bh & 15;
#pragma unroll
    for (int r = 0; r < 16; r++) {
      const int ql = (r & 3) + 8 * (r >> 2) + 4 * h;
      const float A = fa[r >> 2][r & 3], B = fb[r >> 2][r & 3];
      u16* orow = o + ((size_t)b * 2048 + qrow0 + ql) * 1024 + hh * 64;
      orow[rq] = f2bf(oacc0[r] * A + cw[ql * 64 + rq] * B);
      orow[32 + rq] = f2bf(oacc1[r] * A + cw[ql * 64 + 32 + rq] * B);
    }
  }
}

extern "C" void kernel_launch(void* const* d_in, const int* in_sizes, int n_in,
                              void* d_out, int out_size, void* d_ws, size_t ws_size,
                              hipStream_t stream) {
  (void)in_sizes; (void)n_in; (void)out_size; (void)ws_size;
  const float* x     = (const float*)d_in[0];
  const float* ln1_g = (const float*)d_in[1];
  const float* ln1_b = (const float*)d_in[2];
  const float* wq    = (const float*)d_in[3];
  const float* bq    = (const float*)d_in[4];
  const float* wk    = (const float*)d_in[5];
  const float* bk    = (const float*)d_in[6];
  const float* wv    = (const float*)d_in[7];
  const float* bv    = (const float*)d_in[8];
  const float* wo    = (const float*)d_in[9];
  const float* bo    = (const float*)d_in[10];
  const float* ln2_g = (const float*)d_in[11];
  const float* ln2_b = (const float*)d_in[12];
  const float* w1    = (const float*)d_in[13];
  const float* b1    = (const float*)d_in[14];
  const float* w2    = (const float*)d_in[15];
  const float* b2    = (const float*)d_in[16];
  const float* gmsa  = (const float*)d_in[17];
  const float* gmlp  = (const float*)d_in[18];
  float* out = (float*)d_out;

  char* w = (char*)d_ws;
  auto alloc = [&](size_t bytes) {
    char* p = w;
    w += (bytes + 255) & ~(size_t)255;
    return p;
  };
  u16* h1     = (u16*)alloc(4096UL * 1024 * 2);
  u16* wqkv_t = (u16*)alloc(3072UL * 1024 * 2);
  u16* wo_t   = (u16*)alloc(1024UL * 1024 * 2);
  u16* w1_t   = (u16*)alloc(4096UL * 1024 * 2);
  u16* w2_t   = (u16*)alloc(1024UL * 4096 * 2);
  float* bqkv = (float*)alloc(3072UL * 4);
  u16* qkv    = (u16*)alloc(4096UL * 3072 * 2);
  u16* q_r    = (u16*)alloc(65536UL * 64 * 2);
  u16* k_r    = (u16*)alloc(65536UL * 64 * 2);
  u16* v_t    = (u16*)alloc(65536UL * 64 * 2);
  u16* o_at   = (u16*)alloc(4096UL * 1024 * 2);
  u16* h2     = (u16*)alloc(4096UL * 1024 * 2);
  u16* g1     = (u16*)alloc(4096UL * 4096 * 2);

  // weights -> bf16, transposed to (N x K); qkv packed [wq; wk; wv]
  tcvt_k<<<dim3(32, 32), 256, 0, stream>>>(wq, wqkv_t, 1024, 1024);
  tcvt_k<<<dim3(32, 32), 256, 0, stream>>>(wk, wqkv_t + 1024 * 1024, 1024, 1024);
  tcvt_k<<<dim3(32, 32), 256, 0, stream>>>(wv, wqkv_t + 2048 * 1024, 1024, 1024);
  tcvt_k<<<dim3(32, 32), 256, 0, stream>>>(wo, wo_t, 1024, 1024);
  tcvt_k<<<dim3(32, 128), 256, 0, stream>>>(w1, w1_t, 1024, 4096);
  tcvt_k<<<dim3(128, 32), 256, 0, stream>>>(w2, w2_t, 4096, 1024);
  hipMemcpyAsync(bqkv,        bq, 1024 * sizeof(float), hipMemcpyDeviceToDevice, stream);
  hipMemcpyAsync(bqkv + 1024, bk, 1024 * sizeof(float), hipMemcpyDeviceToDevice, stream);
  hipMemcpyAsync(bqkv + 2048, bv, 1024 * sizeof(float), hipMemcpyDeviceToDevice, stream);

  // attention branch
  ln_k<<<4096, 256, 0, stream>>>(x, ln1_g, ln1_b, h1);
  gemm_bt<0, 128><<<dim3(32, 24), 256, 0, stream>>>(h1, wqkv_t, bqkv, nullptr, nullptr, qkv, 4096, 3072, 1024);
  rope_k<<<dim3(8192, 2), 256, 0, stream>>>(qkv, q_r, k_r);
  vtrans_k<<<1024, 256, 0, stream>>>(qkv, v_t);
  attn_k<<<dim3(16, 32), 512, 0, stream>>>(q_r, k_r, v_t, o_at);
  // x1 = x + gate_msa * (o @ wo + bo)  -> written to d_out (fp32)
  gemm_bt<2, 64><<<dim3(32, 16), 256, 0, stream>>>(o_at, wo_t, bo, x, gmsa, out, 4096, 1024, 1024);

  // MLP branch (accumulates into d_out)
  ln_k<<<4096, 256, 0, stream>>>(out, ln2_g, ln2_b, h2);
  gemm_bt<1, 128><<<dim3(32, 32), 256, 0, stream>>>(h2, w1_t, b1, nullptr, nullptr, g1, 4096, 4096, 1024);
  gemm_bt<3, 64><<<dim3(32, 16), 256, 0, stream>>>(g1, w2_t, b2, nullptr, gmlp, out, 4096, 1024, 4096);
}